// Round 1
// baseline (1268.823 us; speedup 1.0000x reference)
//
#include <hip/hip_runtime.h>
#include <math.h>

#define MASK_ID 50264
#define LEFT_ID 4832
#define RIGHT_ID 2

static constexpr int B = 8, S = 512, H = 16, V = 50265;
static constexpr int NGROUP = 3 * B * H;            // 384 (l,b,h) groups
static constexpr int CHUNKS = 8;                    // blocks per group for stats
static constexpr int NBLK_STATS = NGROUP * CHUNKS;  // 3072
static constexpr int F4_PER_GROUP = S * S / 4;      // 65536 float4 per group
static constexpr int F4_PER_CHUNK = F4_PER_GROUP / CHUNKS;  // 8192
static constexpr int F4_PER_THREAD = F4_PER_CHUNK / 256;    // 32

struct WS {
    double partial_sum[NBLK_STATS];
    double partial_ssq[NBLK_STATS];
    int mask_pos[B], left[B], right[B];
    double s_i[3 * B];
    float anchor[3][B][7];
    double posb[B], negb[B];
};

// ---------------- Kernel 1: full-tensor stats over attn (dominant) ------------
__global__ void k_stats(const float4* __restrict__ attn, WS* __restrict__ ws) {
    const int blk = blockIdx.x;
    const int t = threadIdx.x;
    const size_t base = (size_t)blk * F4_PER_CHUNK;
    double s = 0.0, ss = 0.0;
#pragma unroll
    for (int i = 0; i < F4_PER_THREAD; ++i) {
        float4 v = attn[base + (size_t)i * 256 + t];
        double a = v.x, b = v.y, c = v.z, d = v.w;
        s += (a + b) + (c + d);
        ss += (a * a + b * b) + (c * c + d * d);
    }
    __shared__ double sm0[256], sm1[256];
    sm0[t] = s; sm1[t] = ss;
    __syncthreads();
    for (int off = 128; off > 0; off >>= 1) {
        if (t < off) { sm0[t] += sm0[t + off]; sm1[t] += sm1[t + off]; }
        __syncthreads();
    }
    if (t == 0) { ws->partial_sum[blk] = sm0[0]; ws->partial_ssq[blk] = sm1[0]; }
}

// --------- Kernel 2: marker positions + mask-row log-softmax + pos/neg --------
__global__ void k_prep(const float* __restrict__ logits,
                       const float* __restrict__ pos_w,
                       const float* __restrict__ neg_w,
                       const int* __restrict__ ids,
                       WS* __restrict__ ws) {
    const int b = blockIdx.x;   // 8 blocks
    const int t = threadIdx.x;  // 512 threads
    __shared__ int si[3 * 512];
    {
        int id = ids[b * S + t];
        si[t]        = (id == MASK_ID)  ? t : S;
        si[512 + t]  = (id == LEFT_ID)  ? t : S;
        si[1024 + t] = (id == RIGHT_ID) ? t : S;
    }
    __syncthreads();
    for (int off = 256; off > 0; off >>= 1) {
        if (t < off) {
            si[t]        = min(si[t],        si[t + off]);
            si[512 + t]  = min(si[512 + t],  si[512 + t + off]);
            si[1024 + t] = min(si[1024 + t], si[1024 + t + off]);
        }
        __syncthreads();
    }
    const int mp = (si[0] == S) ? 0 : si[0];
    if (t == 0) {
        ws->mask_pos[b] = mp;
        ws->left[b]  = (si[512]  == S) ? 0 : si[512];
        ws->right[b] = (si[1024] == S) ? 0 : si[1024];
    }

    const float* __restrict__ row = logits + ((size_t)b * S + mp) * (size_t)V;
    // pass 1: max
    float m = -INFINITY;
    for (int i = t; i < V; i += 512) m = fmaxf(m, row[i]);
    __shared__ float sf[512];
    sf[t] = m; __syncthreads();
    for (int off = 256; off > 0; off >>= 1) {
        if (t < off) sf[t] = fmaxf(sf[t], sf[t + off]);
        __syncthreads();
    }
    m = sf[0];
    // pass 2: sum exp (double accumulate; row is L2-resident now)
    double sum = 0.0;
    for (int i = t; i < V; i += 512) sum += (double)expf(row[i] - m);
    __shared__ double sd[512];
    sd[t] = sum; __syncthreads();
    for (int off = 256; off > 0; off >>= 1) {
        if (t < off) sd[t] += sd[t + off];
        __syncthreads();
    }
    if (t == 0) {
        const double logZ = log(sd[0]) + (double)m;
        const int PIDS[3] = {1313, 372, 205};
        const int NIDS[3] = {2362, 699, 103};
        // softmax of pos_w / neg_w (3 elements each)
        double p0 = pos_w[0], p1 = pos_w[1], p2 = pos_w[2];
        double pm = fmax(fmax(p0, p1), p2);
        double e0 = exp(p0 - pm), e1 = exp(p1 - pm), e2 = exp(p2 - pm);
        double es = e0 + e1 + e2;
        double pos = ((double)row[PIDS[0]] - logZ) * (e0 / es)
                   + ((double)row[PIDS[1]] - logZ) * (e1 / es)
                   + ((double)row[PIDS[2]] - logZ) * (e2 / es);
        double n0 = neg_w[0], n1 = neg_w[1], n2 = neg_w[2];
        double nm = fmax(fmax(n0, n1), n2);
        double f0 = exp(n0 - nm), f1 = exp(n1 - nm), f2 = exp(n2 - nm);
        double fs = f0 + f1 + f2;
        double neg = ((double)row[NIDS[0]] - logZ) * (f0 / fs)
                   + ((double)row[NIDS[1]] - logZ) * (f1 / fs)
                   + ((double)row[NIDS[2]] - logZ) * (f2 / fs);
        ws->posb[b] = pos;
        ws->negb[b] = neg;
    }
}

// ------ Kernel 3: per-(l,b) masked-row layernorm + span dot + anchors --------
__global__ void k_row(const float* __restrict__ attn,
                      const float* __restrict__ lnw,
                      const float* __restrict__ lnb,
                      WS* __restrict__ ws) {
    const int l = blockIdx.x >> 3, b = blockIdx.x & 7;  // 24 blocks
    const int t = threadIdx.x;                           // 256 threads
    __shared__ float2 st[H];
    if (t < H) {
        const int g = (l * B + b) * H + t;
        double s = 0.0, ss = 0.0;
        for (int c = 0; c < CHUNKS; ++c) {
            s  += ws->partial_sum[g * CHUNKS + c];
            ss += ws->partial_ssq[g * CHUNKS + c];
        }
        const double N = (double)(S * S);
        const double mu = s / N;
        const double var = ss / N - mu * mu;
        st[t] = make_float2((float)mu, (float)(1.0 / sqrt(var + 1e-5)));
    }
    __syncthreads();
    const int r = ws->mask_pos[b];
    const int lo = ws->left[b] + 1, hi = ws->right[b] - 2;
    const size_t gbase = (((size_t)l * B + b) * H) * (size_t)(S * S);
    double acc = 0.0;
    for (int h = 0; h < H; ++h) {
        const float2 stat = st[h];
        const float* __restrict__ rowp = attn + gbase + (size_t)h * S * S + (size_t)r * S;
#pragma unroll
        for (int k = 0; k < 2; ++k) {
            const int q = t + k * 256;
            const float x = rowp[q];
            const float v = fabsf((x - stat.x) * stat.y * lnw[r * S + q] + lnb[r * S + q]);
            if (q >= lo && q <= hi) acc += (double)v;
        }
    }
    __shared__ double sd[256];
    sd[t] = acc; __syncthreads();
    for (int off = 128; off > 0; off >>= 1) {
        if (t < off) sd[t] += sd[t + off];
        __syncthreads();
    }
    if (t == 0) ws->s_i[l * B + b] = sd[0];
    if (t < 7) {
        float a = 0.f;
        for (int h = 0; h < H; ++h)
            a += attn[gbase + (size_t)h * S * S + 4 * S + t];
        ws->anchor[l][b][t] = a / 16.0f;
    }
}

// ---------------- Kernel 4: scan + supcon + final losses ---------------------
__global__ void k_final(const int* __restrict__ labels,
                        WS* __restrict__ ws,
                        float* __restrict__ out) {
    if (threadIdx.x != 0 || blockIdx.x != 0) return;
    double t = 0.0, ba = 0.0, layer_att = 0.0, gap = 0.0;
    int lab[B];
    for (int i = 0; i < B; ++i) lab[i] = labels[i];
    for (int l = 0; l < 3; ++l) {
        // scan (carried across layers)
        for (int b = 0; b < B; ++b) {
            t = (t + ws->s_i[l * B + b]) / 16.0;
            ba += t;
        }
        ba /= (double)(B * 10);
        layer_att += ba;
        // supcon on anchor [B,7]
        const float* A = &ws->anchor[l][0][0];
        double n[B];
        for (int i = 0; i < B; ++i) {
            double s2 = 0.0;
            for (int k = 0; k < 7; ++k) { double a = A[i * 7 + k]; s2 += a * a; }
            n[i] = fmax(sqrt(s2), 1e-8);
        }
        double e[B][B]; double nss[B];
        for (int i = 0; i < B; ++i) {
            double rs = 0.0;
            for (int j = 0; j < B; ++j) {
                double dot = 0.0;
                for (int k = 0; k < 7; ++k) dot += (double)A[i * 7 + k] * (double)A[j * 7 + k];
                double sim = dot / (n[i] * n[j]);
                e[i][j] = exp(sim / 0.5);
                if (lab[i] != lab[j]) rs += e[i][j];
            }
            nss[i] = rs;
        }
        double lsum = 0.0; int cnt = 0;
        for (int i = 0; i < B; ++i) {
            for (int j = 0; j < B; ++j) {
                const bool same = (lab[i] == lab[j]);
                const double sij = same ? e[i][j] : 0.0;
                const double ratio = sij / (sij + nss[i]);
                const double l0 = log((same ? 0.0 : 1.0) + ratio + ((i == j) ? 1.0 : 0.0));
                if (l0 != 0.0) { lsum += l0; cnt++; }
            }
        }
        gap += lsum / (double)cnt;
    }
    const double loss_1 = gap / 3.0;
    const double loss_2 = layer_att / 3.0;
    double loss_3 = 0.0;
    for (int b = 0; b < B; ++b) {
        const double ng = ws->negb[b], ps = ws->posb[b];
        out[b * 2 + 0] = (float)ng;
        out[b * 2 + 1] = (float)ps;
        const double mx = fmax(ng, ps);
        const double lz = mx + log(exp(ng - mx) + exp(ps - mx));
        loss_3 -= ((lab[b] == 0) ? ng : ps) - lz;
    }
    loss_3 /= (double)B;
    const double loss = 0.7 * loss_3 + 0.15 * loss_1 + 0.15 * loss_2;
    out[16] = (float)loss;
    out[17] = (float)loss_1;
    out[18] = (float)loss_2;
    out[19] = (float)loss_3;
}

extern "C" void kernel_launch(void* const* d_in, const int* in_sizes, int n_in,
                              void* d_out, int out_size, void* d_ws, size_t ws_size,
                              hipStream_t stream) {
    const float* logits = (const float*)d_in[0];
    const float* attn   = (const float*)d_in[1];
    const float* lnw    = (const float*)d_in[2];
    const float* lnb    = (const float*)d_in[3];
    const float* pos_w  = (const float*)d_in[4];
    const float* neg_w  = (const float*)d_in[5];
    const int*   ids    = (const int*)d_in[6];
    // d_in[7] = attention_mask (unused by the reference)
    const int*   labels = (const int*)d_in[8];
    WS* ws = (WS*)d_ws;
    float* out = (float*)d_out;

    k_stats<<<NBLK_STATS, 256, 0, stream>>>((const float4*)attn, ws);
    k_prep<<<B, 512, 0, stream>>>(logits, pos_w, neg_w, ids, ws);
    k_row<<<24, 256, 0, stream>>>(attn, lnw, lnb, ws);
    k_final<<<1, 64, 0, stream>>>(labels, ws, out);
}